// Round 16
// baseline (99.753 us; speedup 1.0000x reference)
//
#include <hip/hip_runtime.h>
#include <hip/hip_bf16.h>

// Problem constants (B=2, N=2048, E=1024, H=16, D=64)
static constexpr int CB = 2, CN = 2048, CE = 1024, CH = 16, CD = 64;
static constexpr int CM = CB * CN;          // 4096 rows
// embed_dim**-0.5 with log2(e) folded in: attention runs in exp2 domain
#define SCALE_Q (1.4426950408889634f / 32.0f)

typedef __attribute__((ext_vector_type(8))) short short8;     // 8 x bf16 (MFMA A/B frag)
typedef __attribute__((ext_vector_type(4))) float f32x4;      // 16x16 C/D frag
typedef __attribute__((ext_vector_type(16))) float f32x16;    // 32x32 C/D frag
typedef __attribute__((ext_vector_type(4))) float f4;
typedef __attribute__((ext_vector_type(4))) unsigned short u16x4;

#define MFMA16(a, b, c) __builtin_amdgcn_mfma_f32_16x16x32_bf16((a), (b), (c), 0, 0, 0)
#define MFMA32(a, b, c) __builtin_amdgcn_mfma_f32_32x32x16_bf16((a), (b), (c), 0, 0, 0)

static __device__ __forceinline__ unsigned short f2bf(float f) {
  union { __hip_bfloat16 h; unsigned short u; } cv;
  cv.h = __float2bfloat16(f);
  return cv.u;
}
static __device__ __forceinline__ unsigned int pk2bf(float lo, float hi) {
  return (unsigned int)f2bf(lo) | ((unsigned int)f2bf(hi) << 16);
}

typedef unsigned int u32;
static __device__ __forceinline__ void gload16(const void* g, void* l) {
  __builtin_amdgcn_global_load_lds(
      (const __attribute__((address_space(1))) u32*)g,
      (__attribute__((address_space(3))) u32*)l, 16, 0, 0);
}

// counted-vmcnt sync point (T4): tile ready, deeper prefetch stays in flight
#define SYNC_V(NSTR)                                             \
  do {                                                           \
    asm volatile("s_waitcnt vmcnt(" NSTR ")" ::: "memory");      \
    __builtin_amdgcn_s_barrier();                                \
    __builtin_amdgcn_sched_barrier(0);                           \
  } while (0)
#define SYNC_L()                                                 \
  do {                                                           \
    asm volatile("s_waitcnt lgkmcnt(0)" ::: "memory");           \
    __builtin_amdgcn_s_barrier();                                \
    __builtin_amdgcn_sched_barrier(0);                           \
  } while (0)
// pin vmem issue-group order: the counted-vmcnt ledger depends on it (r10/r11)
#define FENCE() __builtin_amdgcn_sched_barrier(0)

// ---------------------------------------------------------------------------
// prep: fused weight transposes (f32 [R][C] -> bf16 [C][R]) + mask compaction.
// Blocks [0,1024): Wq; [1024,3072): Wkv; [3072,4096): Wo; [4096,4098): mask.
// ---------------------------------------------------------------------------
__global__ __launch_bounds__(256) void prep(
    const float* __restrict__ Wq, const float* __restrict__ Wkv,
    const float* __restrict__ Wo, unsigned short* __restrict__ WqT,
    unsigned short* __restrict__ WkvT, unsigned short* __restrict__ WoT,
    const int* __restrict__ mask, int* __restrict__ cidx, int* __restrict__ cnt) {
  __shared__ float tile[32][33];
  __shared__ int tsum[256];
  const int bid = blockIdx.x;
  const int t = threadIdx.x;
  if (bid < 4096) {
    const float* in; unsigned short* out; int C, tb;
    if (bid < 1024)      { in = Wq;  out = WqT;  C = 1024; tb = bid; }
    else if (bid < 3072) { in = Wkv; out = WkvT; C = 2048; tb = bid - 1024; }
    else                 { in = Wo;  out = WoT;  C = 1024; tb = bid - 3072; }
    const int R = 1024;
    int tc = C >> 5;
    int bc = tb % tc, br = tb / tc;
    int c = t & 31, r0 = t >> 5;
#pragma unroll
    for (int i = 0; i < 4; ++i) {
      int r = r0 + i * 8;
      tile[r][c] = in[(size_t)(br * 32 + r) * C + bc * 32 + c];
    }
    __syncthreads();
#pragma unroll
    for (int i = 0; i < 4; ++i) {
      int r = r0 + i * 8;
      out[(size_t)(bc * 32 + r) * R + br * 32 + c] = f2bf(tile[c][r]);
    }
  } else {
    const int b = bid - 4096;
    int m[8], s = 0;
#pragma unroll
    for (int i = 0; i < 8; ++i) {
      m[i] = mask[b * CN + t * 8 + i] != 0;
      s += m[i];
    }
    tsum[t] = s;
    __syncthreads();
    if (t == 0) {
      int acc = 0;
      for (int i = 0; i < 256; ++i) { int v = tsum[i]; tsum[i] = acc; acc += v; }
      cnt[b] = acc;
    }
    __syncthreads();
    int pos = tsum[t];
#pragma unroll
    for (int i = 0; i < 8; ++i)
      if (m[i]) cidx[b * CN + pos++] = t * 8 + i;
  }
}

// ---------------------------------------------------------------------------
// GEMM body: BM=64 x BN=128, BK=64, DEPTH-2 prefetch over 3 LDS buffers,
// counted-vmcnt barriers (r16 = r14 base + r11's depth-2 ledger at BK=64:
// lookahead ~1200 cyc > ~900 cyc HBM latency -> load wait fully hidden).
// A f32: reg-load 2 tiles ahead (two NAMED reg sets, rule #20), cvt+ds_write
// 1 tile ahead into PADDED rows. A bf16 / B: gload_lds, both-sides XOR swz.
// vmem ledger (group-granular, FENCE-pinned; AWRITE@tt implicitly retires
// through A(tt+1) -- over-drain safe):
//   AF32 iter issues [A(tt+2) f4 x4 | B(tt+2) gload x4]; at sync@tt the
//   newer ops = A/B(tt+1) + A/B(tt+2) = 16 -> steady vmcnt(16); tails 8, 0.
//   bf16 iter issues 6 gloads -> steady vmcnt(12); tails 6, 0.
// GATHER: rows via cidx; blocks beyond ceil(cnt/64) exit.
// VSPLIT: cols < CE -> xk [M][CE]; cols >= CE -> xvT [CB][CE][CN].
// ---------------------------------------------------------------------------
template <bool AF32, bool OUT_BF16, bool VSPLIT, bool GATHER>
static __device__ __forceinline__ void gemm_body(
    char* lds, int bm, int bn,
    const void* __restrict__ Ap, const unsigned short* __restrict__ Bt,
    const float* __restrict__ bias, void* __restrict__ C0,
    unsigned short* __restrict__ C1, int N, int K, float outscale,
    const int* __restrict__ cidx, const int* __restrict__ cnt) {
  constexpr int ASTR = AF32 ? 72 : 64;         // elems/row (pad ds_write path)
  constexpr int ABYTES = 64 * ASTR * 2;        // per-buffer A bytes
  unsigned short* As = (unsigned short*)lds;   // [3][64*ASTR]
  char* Bs = lds + 3 * ABYTES;                 // [3][128*128B]
  const int m0 = bm << 6, n0 = bn << 7;

  if constexpr (GATHER) {
    const int bb = m0 >> 11;               // batch (2048 rows each)
    const int ru = min((cnt[bb] + 63) & ~63, CN);
    if ((m0 & 2047) >= ru) return;         // uniform block exit
  }

  const int t = threadIdx.x;
  const int lane = t & 63, w = t >> 6;
  const int wr = w >> 1, wc = w & 1;
  const int fr = lane & 15, fg = lane >> 4;

  // staging geometry: 16B slots; s = t + i*256 keeps (s&7) and (row&7) fixed
  const int sw8 = (t & 7) ^ ((t >> 3) & 7);    // pre-swizzled source slot

  // AF32 A staging: row = t>>2, ach = t&3 covers f32 [ch*8,+8) and [32+ch*8,+8)
  const int ach = t & 3;
  size_t arow;                                 // A source row (f32 path)
  {
    int gr = m0 + (t >> 2);
    if constexpr (GATHER) {
      int bb = gr >> 11, r = gr & 2047;
      int cb_ = cnt[bb];
      int cr = r < cb_ ? r : (cb_ > 0 ? cb_ - 1 : 0);
      gr = bb * CN + cidx[bb * CN + cr];
    }
    arow = (size_t)gr * K;
  }

  f32x4 acc[2][4];
#pragma unroll
  for (int i = 0; i < 2; ++i)
#pragma unroll
    for (int j = 0; j < 4; ++j) acc[i][j] = (f32x4){0.f, 0.f, 0.f, 0.f};

  auto BSTAGE = [&](int bi, int k0) {
#pragma unroll
    for (int i = 0; i < 4; ++i) {
      int s = t + i * 256;                     // row = s>>3 (128 rows x 8 slots)
      gload16(Bt + (size_t)(n0 + (s >> 3)) * K + k0 + sw8 * 8,
              Bs + bi * 128 * 128 + s * 16);
    }
    if constexpr (!AF32) {
#pragma unroll
      for (int i = 0; i < 2; ++i) {
        int s = t + i * 256;                   // row = s>>3 (64 rows x 8 slots)
        gload16((const unsigned short*)Ap + (size_t)(m0 + (s >> 3)) * K + k0 + sw8 * 8,
                (char*)As + bi * 64 * 128 + s * 16);
      }
    }
  };

  const int nt = K >> 6;                       // 16 iterations (even)
  f4 sA0, sA1, sA2, sA3, sB0, sB1, sB2, sB3;   // two named A reg sets

  auto ALOAD_TO = [&](int k0, f4& r0, f4& r1, f4& r2, f4& r3) {
    const float* src = (const float*)Ap + arow + k0 + ach * 8;
    r0 = *(const f4*)src;
    r1 = *(const f4*)(src + 4);
    r2 = *(const f4*)(src + 32);
    r3 = *(const f4*)(src + 36);
  };
  auto AWRITE_FROM = [&](int bi, f4& r0, f4& r1, f4& r2, f4& r3) {
    short8 av0, av1;
#pragma unroll
    for (int j = 0; j < 4; ++j) {
      av0[j] = (short)f2bf(r0[j]);
      av0[4 + j] = (short)f2bf(r1[j]);
      av1[j] = (short)f2bf(r2[j]);
      av1[4 + j] = (short)f2bf(r3[j]);
    }
    unsigned short* dst = As + bi * 64 * ASTR + (t >> 2) * ASTR;
    *(short8*)&dst[ach * 8] = av0;
    *(short8*)&dst[32 + ach * 8] = av1;
  };

  // prologue (FENCE-pinned groups): A(0)->LDS(0), B(0), A(1)->setB, B(1)
  if constexpr (AF32) {
    ALOAD_TO(0, sA0, sA1, sA2, sA3);           // implicit wait drains A(0)
    AWRITE_FROM(0, sA0, sA1, sA2, sA3);
  }
  FENCE();
  BSTAGE(0, 0);
  FENCE();
  if constexpr (AF32) ALOAD_TO(64, sB0, sB1, sB2, sB3);
  FENCE();
  BSTAGE(1, 64);
  asm volatile("s_waitcnt lgkmcnt(0)" ::: "memory");  // A(0) ds_write retired

  // STEP(tt): load A(tt+2)->la*, stage B(tt+2); wait; mfma(tt);
  //           AWRITE tile tt+1 from wa*; SYNC_L.
  auto STEP = [&](int tt, f4& la0, f4& la1, f4& la2, f4& la3,
                  f4& wa0, f4& wa1, f4& wa2, f4& wa3) {
    const int cur = tt % 3;
    const bool p2 = (tt + 2) < nt;
    if (p2) {
      if constexpr (AF32) ALOAD_TO((tt + 2) << 6, la0, la1, la2, la3);
      FENCE();
      BSTAGE((tt + 2) % 3, (tt + 2) << 6);
    }
    if (p2) {
      if constexpr (AF32) SYNC_V("16"); else SYNC_V("12");
    } else if (tt + 1 < nt) {
      if constexpr (AF32) SYNC_V("8"); else SYNC_V("6");
    } else {
      SYNC_V("0");
    }

    short8 af[2][2], bfv[4][2];
#pragma unroll
    for (int mi = 0; mi < 2; ++mi) {
      const int r = wr * 32 + mi * 16 + fr;
#pragma unroll
      for (int kk = 0; kk < 2; ++kk) {
        if constexpr (AF32) {
          af[mi][kk] = *(const short8*)&As[cur * 64 * ASTR + r * ASTR + kk * 32 + fg * 8];
        } else {
          const int sl = (kk * 4 + fg) ^ (r & 7);
          af[mi][kk] = *(const short8*)((char*)As + cur * 64 * 128 + r * 128 + sl * 16);
        }
      }
    }
#pragma unroll
    for (int ni = 0; ni < 4; ++ni) {
      const int r = wc * 64 + ni * 16 + fr;
#pragma unroll
      for (int kk = 0; kk < 2; ++kk) {
        const int sl = (kk * 4 + fg) ^ (r & 7);
        bfv[ni][kk] = *(const short8*)(Bs + cur * 128 * 128 + r * 128 + sl * 16);
      }
    }
#pragma unroll
    for (int kk = 0; kk < 2; ++kk)
#pragma unroll
      for (int mi = 0; mi < 2; ++mi)
#pragma unroll
        for (int ni = 0; ni < 4; ++ni)
          acc[mi][ni] = MFMA16(af[mi][kk], bfv[ni][kk], acc[mi][ni]);

    if (tt + 1 < nt) {
      if constexpr (AF32)   // write tile tt+1 (regs loaded at iter tt-1)
        AWRITE_FROM((tt + 1) % 3, wa0, wa1, wa2, wa3);
    }
    SYNC_L();               // reads retired + A write visible for tt+1
  };

  for (int t2 = 0; t2 < nt; t2 += 2) {
    STEP(t2,     sA0, sA1, sA2, sA3, sB0, sB1, sB2, sB3);  // even
    STEP(t2 + 1, sB0, sB1, sB2, sB3, sA0, sA1, sA2, sA3);  // odd
  }

  // Epilogue: 16x16 C/D frag mapping col = lane&15, row = (lane>>4)*4 + reg
#pragma unroll
  for (int mi = 0; mi < 2; ++mi) {
    int row0 = m0 + wr * 32 + mi * 16 + fg * 4;
#pragma unroll
    for (int ni = 0; ni < 4; ++ni) {
      int col = n0 + wc * 64 + ni * 16 + fr;
      float bv = bias[col];
      if constexpr (VSPLIT) {
        if (col < CE) {
#pragma unroll
          for (int rr = 0; rr < 4; ++rr)
            ((unsigned short*)C0)[(size_t)(row0 + rr) * CE + col] =
                f2bf((acc[mi][ni][rr] + bv) * outscale);
        } else {
          u16x4 pk;
#pragma unroll
          for (int rr = 0; rr < 4; ++rr) pk[rr] = f2bf((acc[mi][ni][rr] + bv) * outscale);
          int b = row0 / CN, n = row0 % CN;   // 4 consecutive n -> one 8B store
          *(u16x4*)&C1[((size_t)b * CE + (col - CE)) * CN + n] = pk;
        }
      } else if constexpr (OUT_BF16) {
#pragma unroll
        for (int rr = 0; rr < 4; ++rr)
          ((unsigned short*)C0)[(size_t)(row0 + rr) * N + col] =
              f2bf((acc[mi][ni][rr] + bv) * outscale);
      } else {
#pragma unroll
        for (int rr = 0; rr < 4; ++rr)
          ((float*)C0)[(size_t)(row0 + rr) * N + col] = (acc[mi][ni][rr] + bv) * outscale;
      }
    }
  }
}

// Fused Q-proj + KV-proj. Balanced XCD swizzle (r14-proven): bm % 8 == raw % 8
// within each segment -> A-panel L2 colocation without load imbalance.
__global__ __launch_bounds__(256) void gemm_qkv(
    const float* __restrict__ q, const unsigned short* __restrict__ WqT,
    const float* __restrict__ bq, unsigned short* __restrict__ xq,
    const float* __restrict__ kv, const unsigned short* __restrict__ WkvT,
    const float* __restrict__ bkv, unsigned short* __restrict__ xk,
    unsigned short* __restrict__ xvT,
    const int* __restrict__ cidx, const int* __restrict__ cnt) {
  __shared__ char lds[3 * 64 * 72 * 2 + 3 * 128 * 128];  // 76800 B -> 2 blk/CU
  const int raw = blockIdx.x;
  if (raw < 512) {                  // Q: 64 bm x 8 bn
    const int k = raw & 7, j = raw >> 3;
    gemm_body<true, true, false, false>(lds, k + 8 * (j >> 3), j & 7, q, WqT,
                                        bq, xq, nullptr, CE, CE, SCALE_Q,
                                        nullptr, nullptr);
  } else {                          // KV: 64 bm x 16 bn
    const int r2 = raw - 512;
    const int k = r2 & 7, j = r2 >> 3;
    gemm_body<true, true, true, true>(lds, k + 8 * (j >> 4), j & 15, kv, WkvT,
                                      bkv, xk, xvT, 2 * CE, CE, 1.0f, cidx, cnt);
  }
}

// O-proj: attn(bf16) @ WoT + bo -> f32 out (same balanced swizzle)
__global__ __launch_bounds__(256) void gemm_o(
    const unsigned short* __restrict__ attnA, const unsigned short* __restrict__ WoT,
    const float* __restrict__ bo, float* __restrict__ out) {
  __shared__ char lds[3 * 64 * 128 + 3 * 128 * 128];  // 73728 B
  const int k = blockIdx.x & 7, j = blockIdx.x >> 3;
  gemm_body<false, false, false, false>(lds, k + 8 * (j >> 3), j & 7,
                                        attnA, WoT, bo, out, nullptr, CE, CE,
                                        1.0f, nullptr, nullptr);
}

// ---------------------------------------------------------------------------
// Flash attention over COMPACTED kv (round-5 validated core, unchanged).
// ---------------------------------------------------------------------------
__global__ __launch_bounds__(256, 2) void attn_fwd(
    unsigned short* __restrict__ xq,        // in: scaled Q; out: attn (in-place)
    const unsigned short* __restrict__ xk,  // compacted K [b][i][e(head)]
    const unsigned short* __restrict__ xvT, // compacted V^T [b][e][i]
    const int* __restrict__ cnt) {
  __shared__ unsigned short Kt[64][72];   // K tile  [c][d], +8 pad
  __shared__ unsigned short Vt[64][72];   // V^T tile [d][c], +8 pad
  __shared__ float dsh[4][32];

  const int bid = blockIdx.x;             // 512 blocks: b*256 + h*16 + qblk
  const int qblk = bid & 15;
  const int h = (bid >> 4) & 15;
  const int b = bid >> 8;
  const int t = threadIdx.x, lane = t & 63, w = t >> 6;
  const int l31 = lane & 31, h5 = lane >> 5;
  const int q0 = qblk * 128 + w * 32;

  const int cntb = cnt[b];
  const int nt = (cntb + 63) >> 6;        // tiles of compacted kv

  // Q B-frags: col q = lane&31, k = dk*16 + h5*8 + j
  short8 qf[4];
  {
    const unsigned short* qp =
        xq + ((size_t)(b * CN + q0 + l31)) * CE + h * CD + h5 * 8;
#pragma unroll
    for (int dk = 0; dk < 4; ++dk) qf[dk] = *(const short8*)(qp + dk * 16);
  }

  f32x16 o[2];
#pragma unroll
  for (int c = 0; c < 2; ++c)
#pragma unroll
    for (int i = 0; i < 16; ++i) o[c][i] = 0.f;
  float ls = 0.f;

  // per-thread staging slots: s = t + p*256; row = s>>3, slot = s&7
  const int r0s = t >> 3, sl0 = t & 7;          // p=0
  const int r1s = r0s + 32, sl1 = sl0;          // p=1 (t+256)

  short8 rk[2], rv[2];
  if (nt > 0) {
    rk[0] = *(const short8*)(xk + ((size_t)(b * CN + r0s)) * CE + h * CD + sl0 * 8);
    rk[1] = *(const short8*)(xk + ((size_t)(b * CN + r1s)) * CE + h * CD + sl1 * 8);
    rv[0] = *(const short8*)(xvT + ((size_t)(b * CE + h * CD + r0s)) * CN + sl0 * 8);
    rv[1] = *(const short8*)(xvT + ((size_t)(b * CE + h * CD + r1s)) * CN + sl1 * 8);
  }

  for (int kt = 0; kt < nt; ++kt) {
    __syncthreads();   // prior iter's LDS reads complete before overwrite
    *(short8*)&Kt[r0s][sl0 * 8] = rk[0];
    *(short8*)&Kt[r1s][sl1 * 8] = rk[1];
    *(short8*)&Vt[r0s][sl0 * 8] = rv[0];
    *(short8*)&Vt[r1s][sl1 * 8] = rv[1];
    __syncthreads();   // writes visible

    // issue next tile's loads early (overlap with compute below)
    if (kt < nt - 1) {
      const int kn = (kt + 1) * 64;
      rk[0] = *(const short8*)(xk + ((size_t)(b * CN + kn + r0s)) * CE + h * CD + sl0 * 8);
      rk[1] = *(const short8*)(xk + ((size_t)(b * CN + kn + r1s)) * CE + h * CD + sl1 * 8);
      rv[0] = *(const short8*)(xvT + ((size_t)(b * CE + h * CD + r0s)) * CN + kn + sl0 * 8);
      rv[1] = *(const short8*)(xvT + ((size_t)(b * CE + h * CD + r1s)) * CN + kn + sl1 * 8);
    }

    // --- S^T = K * Q^T : A = K rows (c), B = Q cols (q) ---
    short8 ka[2][4];
#pragma unroll
    for (int cb = 0; cb < 2; ++cb)
#pragma unroll
      for (int dk = 0; dk < 4; ++dk)
        ka[cb][dk] = *(const short8*)&Kt[cb * 32 + l31][(dk * 2 + h5) * 8];

    f32x16 s2[2];
#pragma unroll
    for (int cb = 0; cb < 2; ++cb) {
#pragma unroll
      for (int i = 0; i < 16; ++i) s2[cb][i] = 0.f;
#pragma unroll
      for (int dk = 0; dk < 4; ++dk)
        s2[cb] = MFMA32(ka[cb][dk], qf[dk], s2[cb]);
    }

    // --- exp2, deferred row-sum, pack (tail tile masks pos >= cnt) ---
    const bool tail = (kt == nt - 1) && (cntb & 63);
    unsigned int U[2][4][2];   // [cb][quad][word]
#pragma unroll
    for (int cb = 0; cb < 2; ++cb) {
      float p[16];
#pragma unroll
      for (int i = 0; i < 16; ++i) {
        float sv = s2[cb][i];
        if (tail) {
          int cpos = kt * 64 + cb * 32 + (i & 3) + 8 * (i >> 2) + 4 * h5;
          sv = (cpos < cntb) ? sv : -30000.f;
        }
        p[i] = __builtin_amdgcn_exp2f(sv);
        ls += p[i];
      }
#pragma unroll
      for (int m = 0; m < 4; ++m) {
        U[cb][m][0] = pk2bf(p[4 * m], p[4 * m + 1]);
        U[cb][m][1] = pk2bf(p[4 * m + 2], p[4 * m + 3]);
      }
    }

    // --- V B-frags; P A-frags via lane^32 exchange; PV ---
    short8 vb[2][4];
#pragma unroll
    for (int nb = 0; nb < 2; ++nb)
#pragma unroll
      for (int kc = 0; kc < 4; ++kc)
        vb[nb][kc] = *(const short8*)&Vt[nb * 32 + l31][(kc * 2 + h5) * 8];

#pragma unroll
    for (int kc = 0; kc < 4; ++kc) {
      const int cb = kc >> 1, k2 = (kc & 1) * 2;
      unsigned int su0 = h5 ? U[cb][k2 + 1][0] : U[cb][k2][0];
      unsigned int su1 = h5 ? U[cb][k2 + 1][1] : U[cb][k2][1];
      unsigned int st0 = h5 ? U[cb][k2][0] : U[cb][k2 + 1][0];
      unsigned int st1 = h5 ? U[cb][k2][1] : U[cb][k2 + 1][1];
      unsigned int x0 = (unsigned int)__shfl_xor((int)st0, 32);
      unsigned int x1 = (unsigned int)__shfl_xor((int)st1, 32);
      union { unsigned int u[4]; short8 v; } pa;
      pa.u[0] = h5 ? x0 : su0;
      pa.u[1] = h5 ? x1 : su1;
      pa.u[2] = h5 ? su0 : x0;
      pa.u[3] = h5 ? su1 : x1;
#pragma unroll
      for (int nb = 0; nb < 2; ++nb)
        o[nb] = MFMA32(pa.v, vb[nb][kc], o[nb]);
    }
  }

  // --- epilogue: denom = 1/(rowsum + 1), broadcast via LDS + barrier ---
  {
    float tot = ls + __shfl_xor(ls, 32);
    if (h5 == 0) dsh[w][l31] = 1.0f / (tot + 1.0f);
  }
  __syncthreads();
#pragma unroll
  for (int m = 0; m < 4; ++m) {
    f4 dn4 = *(const f4*)&dsh[w][m * 8 + h5 * 4];
#pragma unroll
    for (int rr = 0; rr < 4; ++rr) {
      int q = m * 8 + h5 * 4 + rr;
      size_t row = (size_t)(b * CN + q0 + q);
#pragma unroll
      for (int nb = 0; nb < 2; ++nb) {
        float val = o[nb][m * 4 + rr] * dn4[rr];
        xq[row * CE + h * CD + nb * 32 + l31] = f2bf(val);
      }
    }
  }
}

// ---------------------------------------------------------------------------
extern "C" void kernel_launch(void* const* d_in, const int* in_sizes, int n_in,
                              void* d_out, int out_size, void* d_ws, size_t ws_size,
                              hipStream_t stream) {
  const float* q    = (const float*)d_in[0];
  const float* kv   = (const float*)d_in[1];
  const int*   mask = (const int*)d_in[2];
  const float* Wq   = (const float*)d_in[3];
  const float* bq   = (const float*)d_in[4];
  const float* Wkv  = (const float*)d_in[5];
  const float* bkv  = (const float*)d_in[6];
  const float* Wo   = (const float*)d_in[7];
  const float* bo   = (const float*)d_in[8];
  (void)in_sizes; (void)n_in; (void)out_size; (void)ws_size;

  char* ws = (char*)d_ws;   // ~32.1 MB total (attn writes in-place into xq)
  unsigned short* WoT  = (unsigned short*)(ws);                        // 2 MB
  unsigned short* xq   = (unsigned short*)(ws + (2u  << 20));          // 8 MB
  unsigned short* xk   = (unsigned short*)(ws + (10u << 20));          // 8 MB (compact)
  unsigned short* xvT  = (unsigned short*)(ws + (18u << 20));          // 8 MB (compact)
  unsigned short* WqT  = (unsigned short*)(ws + (26u << 20));          // 2 MB
  unsigned short* WkvT = (unsigned short*)(ws + (28u << 20));          // 4 MB
  int*            cidx = (int*)(ws + (32u << 20));                     // 16 KB
  int*            cnt  = (int*)(ws + (32u << 20) + 16384);             // 8 B

  // fused transposes + mask compaction
  prep<<<4098, 256, 0, stream>>>(Wq, Wkv, Wo, WqT, WkvT, WoT, mask, cidx, cnt);

  // fused: xq = (q @ Wq + bq) * SCALE_Q ; compacted xk/xvT = kv[kept] @ Wkv + bkv
  gemm_qkv<<<1536, 256, 0, stream>>>(q, WqT, bq, xq, kv, WkvT, bkv, xk, xvT, cidx, cnt);

  attn_fwd<<<CB * CH * 16, 256, 0, stream>>>(xq, xk, xvT, cnt);

  // out = attn @ Wo + bo  (f32 out; A = xq holds attn result in-place)
  gemm_o<<<512, 256, 0, stream>>>(xq, WoT, bo, (float*)d_out);
}

// Round 17
// 88.527 us; speedup vs baseline: 1.1268x; 1.1268x over previous
//
#include <hip/hip_runtime.h>
#include <hip/hip_bf16.h>

// Problem constants (B=2, N=2048, E=1024, H=16, D=64)
static constexpr int CB = 2, CN = 2048, CE = 1024, CH = 16, CD = 64;
static constexpr int CM = CB * CN;          // 4096 rows
// embed_dim**-0.5 with log2(e) folded in: attention runs in exp2 domain
#define SCALE_Q (1.4426950408889634f / 32.0f)

typedef __attribute__((ext_vector_type(8))) short short8;     // 8 x bf16 (MFMA A/B frag)
typedef __attribute__((ext_vector_type(4))) float f32x4;      // 16x16 C/D frag
typedef __attribute__((ext_vector_type(16))) float f32x16;    // 32x32 C/D frag
typedef __attribute__((ext_vector_type(4))) float f4;
typedef __attribute__((ext_vector_type(4))) unsigned short u16x4;

#define MFMA16(a, b, c) __builtin_amdgcn_mfma_f32_16x16x32_bf16((a), (b), (c), 0, 0, 0)
#define MFMA32(a, b, c) __builtin_amdgcn_mfma_f32_32x32x16_bf16((a), (b), (c), 0, 0, 0)

static __device__ __forceinline__ unsigned short f2bf(float f) {
  union { __hip_bfloat16 h; unsigned short u; } cv;
  cv.h = __float2bfloat16(f);
  return cv.u;
}
static __device__ __forceinline__ unsigned int pk2bf(float lo, float hi) {
  return (unsigned int)f2bf(lo) | ((unsigned int)f2bf(hi) << 16);
}

typedef unsigned int u32;
static __device__ __forceinline__ void gload16(const void* g, void* l) {
  __builtin_amdgcn_global_load_lds(
      (const __attribute__((address_space(1))) u32*)g,
      (__attribute__((address_space(3))) u32*)l, 16, 0, 0);
}

#define SYNC_L()                                                 \
  do {                                                           \
    asm volatile("s_waitcnt lgkmcnt(0)" ::: "memory");           \
    __builtin_amdgcn_s_barrier();                                \
    __builtin_amdgcn_sched_barrier(0);                           \
  } while (0)

// ---------------------------------------------------------------------------
// prep: weight transposes (f32 [R][C] -> bf16 [C][R]) + mask compaction +
// q/kv f32 -> bf16 conversion (r17: kills the AF32 GEMM path entirely).
// Blocks [0,4096): transposes; [4096,4098): mask; [4098,8194): conversions.
// ---------------------------------------------------------------------------
__global__ __launch_bounds__(256) void prep(
    const float* __restrict__ Wq, const float* __restrict__ Wkv,
    const float* __restrict__ Wo, unsigned short* __restrict__ WqT,
    unsigned short* __restrict__ WkvT, unsigned short* __restrict__ WoT,
    const float* __restrict__ q, const float* __restrict__ kv,
    unsigned short* __restrict__ qbf, unsigned short* __restrict__ kvbf,
    const int* __restrict__ mask, int* __restrict__ cidx, int* __restrict__ cnt) {
  __shared__ float tile[32][33];
  __shared__ int tsum[256];
  const int bid = blockIdx.x;
  const int t = threadIdx.x;
  if (bid < 4096) {
    const float* in; unsigned short* out; int C, tb;
    if (bid < 1024)      { in = Wq;  out = WqT;  C = 1024; tb = bid; }
    else if (bid < 3072) { in = Wkv; out = WkvT; C = 2048; tb = bid - 1024; }
    else                 { in = Wo;  out = WoT;  C = 1024; tb = bid - 3072; }
    const int R = 1024;
    int tc = C >> 5;
    int bc = tb % tc, br = tb / tc;
    int c = t & 31, r0 = t >> 5;
#pragma unroll
    for (int i = 0; i < 4; ++i) {
      int r = r0 + i * 8;
      tile[r][c] = in[(size_t)(br * 32 + r) * C + bc * 32 + c];
    }
    __syncthreads();
#pragma unroll
    for (int i = 0; i < 4; ++i) {
      int r = r0 + i * 8;
      out[(size_t)(bc * 32 + r) * R + br * 32 + c] = f2bf(tile[c][r]);
    }
  } else if (bid < 4098) {
    const int b = bid - 4096;
    int m[8], s = 0;
#pragma unroll
    for (int i = 0; i < 8; ++i) {
      m[i] = mask[b * CN + t * 8 + i] != 0;
      s += m[i];
    }
    tsum[t] = s;
    __syncthreads();
    if (t == 0) {
      int acc = 0;
      for (int i = 0; i < 256; ++i) { int v = tsum[i]; tsum[i] = acc; acc += v; }
      cnt[b] = acc;
    }
    __syncthreads();
    int pos = tsum[t];
#pragma unroll
    for (int i = 0; i < 8; ++i)
      if (m[i]) cidx[b * CN + pos++] = t * 8 + i;
  } else {
    // f32 -> bf16 conversion: 2048 blocks per tensor, 2048 elems/block
    const int cb = bid - 4098;
    const float* src = (cb < 2048) ? q : kv;
    unsigned short* dst = (cb < 2048) ? qbf : kvbf;
    const size_t base = (size_t)(cb & 2047) * 2048 + t * 8;
    f4 v0 = *(const f4*)(src + base);
    f4 v1 = *(const f4*)(src + base + 4);
    short8 o;
#pragma unroll
    for (int j = 0; j < 4; ++j) {
      o[j] = (short)f2bf(v0[j]);
      o[4 + j] = (short)f2bf(v1[j]);
    }
    *(short8*)(dst + base) = o;
  }
}

// ---------------------------------------------------------------------------
// GEMM body (r17: single bf16 path — r13-proven structure verbatim):
// BM=64 x BN=128, BK=64, 2-buffer LDS, counted-vmcnt barriers.
// ALL staging via gload_lds with both-sides XOR swizzle (pre-swizzled global
// source slot ^ (row&7), swizzled read) -> conflict-free ds_read_b128.
// vmem ledger: 6 gloads/iter (4 B + 2 A) -> steady vmcnt(6), tail vmcnt(0).
// GATHER: A rows gathered per-lane through cidx; far blocks exit.
// VSPLIT: cols < CE -> xk [M][CE]; cols >= CE -> xvT [CB][CE][CN].
// ---------------------------------------------------------------------------
template <bool OUT_BF16, bool VSPLIT, bool GATHER>
static __device__ __forceinline__ void gemm_body(
    char* lds, int bm, int bn,
    const unsigned short* __restrict__ Abf, const unsigned short* __restrict__ Bt,
    const float* __restrict__ bias, void* __restrict__ C0,
    unsigned short* __restrict__ C1, int N, int K, float outscale,
    const int* __restrict__ cidx, const int* __restrict__ cnt) {
  char* As = lds;                            // [2][64 rows x 128 B]
  char* Bs = lds + 2 * 64 * 128;             // [2][128 rows x 128 B]
  const int m0 = bm << 6, n0 = bn << 7;

  if constexpr (GATHER) {
    const int bb = m0 >> 11;               // batch (2048 rows each)
    const int ru = min((cnt[bb] + 63) & ~63, CN);
    if ((m0 & 2047) >= ru) return;         // uniform block exit
  }

  const int t = threadIdx.x;
  const int lane = t & 63, w = t >> 6;
  const int wr = w >> 1, wc = w & 1;
  const int fr = lane & 15, fg = lane >> 4;

  // staging geometry: 16B slots; s = t + i*256 keeps (s&7) and (row&7) fixed
  const int sw8 = (t & 7) ^ ((t >> 3) & 7);    // pre-swizzled source slot

  // A staging rows (per-lane, gather-aware): rows t>>3 and t>>3 + 32
  size_t arow0, arow1;
  {
    int r0 = m0 + (t >> 3), r1 = r0 + 32;
    if constexpr (GATHER) {
      const int bb = m0 >> 11;
      const int cb_ = cnt[bb];
      int c0 = (r0 & 2047), c1 = (r1 & 2047);
      c0 = c0 < cb_ ? c0 : (cb_ > 0 ? cb_ - 1 : 0);
      c1 = c1 < cb_ ? c1 : (cb_ > 0 ? cb_ - 1 : 0);
      r0 = bb * CN + cidx[bb * CN + c0];
      r1 = bb * CN + cidx[bb * CN + c1];
    }
    arow0 = (size_t)r0 * K;
    arow1 = (size_t)r1 * K;
  }

  f32x4 acc[2][4];
#pragma unroll
  for (int i = 0; i < 2; ++i)
#pragma unroll
    for (int j = 0; j < 4; ++j) acc[i][j] = (f32x4){0.f, 0.f, 0.f, 0.f};

  auto STAGE = [&](int bi, int k0) {
#pragma unroll
    for (int i = 0; i < 4; ++i) {
      int s = t + i * 256;                     // row = s>>3 (128 rows x 8 slots)
      gload16(Bt + (size_t)(n0 + (s >> 3)) * K + k0 + sw8 * 8,
              Bs + bi * 128 * 128 + s * 16);
    }
    gload16(Abf + arow0 + k0 + sw8 * 8, As + bi * 64 * 128 + t * 16);
    gload16(Abf + arow1 + k0 + sw8 * 8, As + bi * 64 * 128 + (t + 256) * 16);
  };

  // prologue: tile 0 (full drain via __syncthreads)
  STAGE(0, 0);
  __syncthreads();

  const int nt = K >> 6;                       // 16 iterations
  int buf = 0;
  for (int tt = 0; tt < nt; ++tt) {
    const bool np = tt < nt - 1;
    if (np) STAGE(buf ^ 1, (tt + 1) << 6);     // 6 gload_lds
    // --- sync A: current tile in LDS; next tile's 6 loads stay in flight
    if (np) asm volatile("s_waitcnt vmcnt(6)" ::: "memory");
    else    asm volatile("s_waitcnt vmcnt(0)" ::: "memory");
    __builtin_amdgcn_s_barrier();
    __builtin_amdgcn_sched_barrier(0);

    short8 af[2][2], bfv[4][2];
#pragma unroll
    for (int mi = 0; mi < 2; ++mi) {
      const int r = wr * 32 + mi * 16 + fr;
#pragma unroll
      for (int kk = 0; kk < 2; ++kk) {
        const int sl = (kk * 4 + fg) ^ (r & 7);
        af[mi][kk] = *(const short8*)(As + buf * 64 * 128 + r * 128 + sl * 16);
      }
    }
#pragma unroll
    for (int ni = 0; ni < 4; ++ni) {
      const int r = wc * 64 + ni * 16 + fr;
#pragma unroll
      for (int kk = 0; kk < 2; ++kk) {
        const int sl = (kk * 4 + fg) ^ (r & 7);
        bfv[ni][kk] = *(const short8*)(Bs + buf * 128 * 128 + r * 128 + sl * 16);
      }
    }
#pragma unroll
    for (int kk = 0; kk < 2; ++kk)
#pragma unroll
      for (int mi = 0; mi < 2; ++mi)
#pragma unroll
        for (int ni = 0; ni < 4; ++ni)
          acc[mi][ni] = MFMA16(af[mi][kk], bfv[ni][kk], acc[mi][ni]);

    // --- sync B: ds_reads retired before this buffer is re-staged
    SYNC_L();
    buf ^= 1;
  }

  // Epilogue: 16x16 C/D frag mapping col = lane&15, row = (lane>>4)*4 + reg
#pragma unroll
  for (int mi = 0; mi < 2; ++mi) {
    int row0 = m0 + wr * 32 + mi * 16 + fg * 4;
#pragma unroll
    for (int ni = 0; ni < 4; ++ni) {
      int col = n0 + wc * 64 + ni * 16 + fr;
      float bv = bias[col];
      if constexpr (VSPLIT) {
        if (col < CE) {
#pragma unroll
          for (int rr = 0; rr < 4; ++rr)
            ((unsigned short*)C0)[(size_t)(row0 + rr) * CE + col] =
                f2bf((acc[mi][ni][rr] + bv) * outscale);
        } else {
          u16x4 pk;
#pragma unroll
          for (int rr = 0; rr < 4; ++rr) pk[rr] = f2bf((acc[mi][ni][rr] + bv) * outscale);
          int b = row0 / CN, n = row0 % CN;   // 4 consecutive n -> one 8B store
          *(u16x4*)&C1[((size_t)b * CE + (col - CE)) * CN + n] = pk;
        }
      } else if constexpr (OUT_BF16) {
#pragma unroll
        for (int rr = 0; rr < 4; ++rr)
          ((unsigned short*)C0)[(size_t)(row0 + rr) * N + col] =
              f2bf((acc[mi][ni][rr] + bv) * outscale);
      } else {
#pragma unroll
        for (int rr = 0; rr < 4; ++rr)
          ((float*)C0)[(size_t)(row0 + rr) * N + col] = (acc[mi][ni][rr] + bv) * outscale;
      }
    }
  }
}

// Fused Q-proj + KV-proj. Balanced XCD swizzle (r14-proven): bm % 8 == raw % 8
// within each segment -> A-panel L2 colocation without load imbalance.
__global__ __launch_bounds__(256) void gemm_qkv(
    const unsigned short* __restrict__ qbf, const unsigned short* __restrict__ WqT,
    const float* __restrict__ bq, unsigned short* __restrict__ xq,
    const unsigned short* __restrict__ kvbf, const unsigned short* __restrict__ WkvT,
    const float* __restrict__ bkv, unsigned short* __restrict__ xk,
    unsigned short* __restrict__ xvT,
    const int* __restrict__ cidx, const int* __restrict__ cnt) {
  __shared__ char lds[2 * 64 * 128 + 2 * 128 * 128];  // 49152 B
  const int raw = blockIdx.x;
  if (raw < 512) {                  // Q: 64 bm x 8 bn
    const int k = raw & 7, j = raw >> 3;
    gemm_body<true, false, false>(lds, k + 8 * (j >> 3), j & 7, qbf, WqT,
                                  bq, xq, nullptr, CE, CE, SCALE_Q,
                                  nullptr, nullptr);
  } else {                          // KV: 64 bm x 16 bn
    const int r2 = raw - 512;
    const int k = r2 & 7, j = r2 >> 3;
    gemm_body<true, true, true>(lds, k + 8 * (j >> 4), j & 15, kvbf, WkvT,
                                bkv, xk, xvT, 2 * CE, CE, 1.0f, cidx, cnt);
  }
}

// O-proj: attn(bf16) @ WoT + bo -> f32 out (same balanced swizzle)
__global__ __launch_bounds__(256) void gemm_o(
    const unsigned short* __restrict__ attnA, const unsigned short* __restrict__ WoT,
    const float* __restrict__ bo, float* __restrict__ out) {
  __shared__ char lds[2 * 64 * 128 + 2 * 128 * 128];  // 49152 B
  const int k = blockIdx.x & 7, j = blockIdx.x >> 3;
  gemm_body<false, false, false>(lds, k + 8 * (j >> 3), j & 7,
                                 attnA, WoT, bo, out, nullptr, CE, CE,
                                 1.0f, nullptr, nullptr);
}

// ---------------------------------------------------------------------------
// Flash attention over COMPACTED kv (round-5 validated core, unchanged).
// ---------------------------------------------------------------------------
__global__ __launch_bounds__(256, 2) void attn_fwd(
    unsigned short* __restrict__ xq,        // in: scaled Q; out: attn (in-place)
    const unsigned short* __restrict__ xk,  // compacted K [b][i][e(head)]
    const unsigned short* __restrict__ xvT, // compacted V^T [b][e][i]
    const int* __restrict__ cnt) {
  __shared__ unsigned short Kt[64][72];   // K tile  [c][d], +8 pad
  __shared__ unsigned short Vt[64][72];   // V^T tile [d][c], +8 pad
  __shared__ float dsh[4][32];

  const int bid = blockIdx.x;             // 512 blocks: b*256 + h*16 + qblk
  const int qblk = bid & 15;
  const int h = (bid >> 4) & 15;
  const int b = bid >> 8;
  const int t = threadIdx.x, lane = t & 63, w = t >> 6;
  const int l31 = lane & 31, h5 = lane >> 5;
  const int q0 = qblk * 128 + w * 32;

  const int cntb = cnt[b];
  const int nt = (cntb + 63) >> 6;        // tiles of compacted kv

  // Q B-frags: col q = lane&31, k = dk*16 + h5*8 + j
  short8 qf[4];
  {
    const unsigned short* qp =
        xq + ((size_t)(b * CN + q0 + l31)) * CE + h * CD + h5 * 8;
#pragma unroll
    for (int dk = 0; dk < 4; ++dk) qf[dk] = *(const short8*)(qp + dk * 16);
  }

  f32x16 o[2];
#pragma unroll
  for (int c = 0; c < 2; ++c)
#pragma unroll
    for (int i = 0; i < 16; ++i) o[c][i] = 0.f;
  float ls = 0.f;

  // per-thread staging slots: s = t + p*256; row = s>>3, slot = s&7
  const int r0s = t >> 3, sl0 = t & 7;          // p=0
  const int r1s = r0s + 32, sl1 = sl0;          // p=1 (t+256)

  short8 rk[2], rv[2];
  if (nt > 0) {
    rk[0] = *(const short8*)(xk + ((size_t)(b * CN + r0s)) * CE + h * CD + sl0 * 8);
    rk[1] = *(const short8*)(xk + ((size_t)(b * CN + r1s)) * CE + h * CD + sl1 * 8);
    rv[0] = *(const short8*)(xvT + ((size_t)(b * CE + h * CD + r0s)) * CN + sl0 * 8);
    rv[1] = *(const short8*)(xvT + ((size_t)(b * CE + h * CD + r1s)) * CN + sl1 * 8);
  }

  for (int kt = 0; kt < nt; ++kt) {
    __syncthreads();   // prior iter's LDS reads complete before overwrite
    *(short8*)&Kt[r0s][sl0 * 8] = rk[0];
    *(short8*)&Kt[r1s][sl1 * 8] = rk[1];
    *(short8*)&Vt[r0s][sl0 * 8] = rv[0];
    *(short8*)&Vt[r1s][sl1 * 8] = rv[1];
    __syncthreads();   // writes visible

    // issue next tile's loads early (overlap with compute below)
    if (kt < nt - 1) {
      const int kn = (kt + 1) * 64;
      rk[0] = *(const short8*)(xk + ((size_t)(b * CN + kn + r0s)) * CE + h * CD + sl0 * 8);
      rk[1] = *(const short8*)(xk + ((size_t)(b * CN + kn + r1s)) * CE + h * CD + sl1 * 8);
      rv[0] = *(const short8*)(xvT + ((size_t)(b * CE + h * CD + r0s)) * CN + kn + sl0 * 8);
      rv[1] = *(const short8*)(xvT + ((size_t)(b * CE + h * CD + r1s)) * CN + kn + sl1 * 8);
    }

    // --- S^T = K * Q^T : A = K rows (c), B = Q cols (q) ---
    short8 ka[2][4];
#pragma unroll
    for (int cb = 0; cb < 2; ++cb)
#pragma unroll
      for (int dk = 0; dk < 4; ++dk)
        ka[cb][dk] = *(const short8*)&Kt[cb * 32 + l31][(dk * 2 + h5) * 8];

    f32x16 s2[2];
#pragma unroll
    for (int cb = 0; cb < 2; ++cb) {
#pragma unroll
      for (int i = 0; i < 16; ++i) s2[cb][i] = 0.f;
#pragma unroll
      for (int dk = 0; dk < 4; ++dk)
        s2[cb] = MFMA32(ka[cb][dk], qf[dk], s2[cb]);
    }

    // --- exp2, deferred row-sum, pack (tail tile masks pos >= cnt) ---
    const bool tail = (kt == nt - 1) && (cntb & 63);
    unsigned int U[2][4][2];   // [cb][quad][word]
#pragma unroll
    for (int cb = 0; cb < 2; ++cb) {
      float p[16];
#pragma unroll
      for (int i = 0; i < 16; ++i) {
        float sv = s2[cb][i];
        if (tail) {
          int cpos = kt * 64 + cb * 32 + (i & 3) + 8 * (i >> 2) + 4 * h5;
          sv = (cpos < cntb) ? sv : -30000.f;
        }
        p[i] = __builtin_amdgcn_exp2f(sv);
        ls += p[i];
      }
#pragma unroll
      for (int m = 0; m < 4; ++m) {
        U[cb][m][0] = pk2bf(p[4 * m], p[4 * m + 1]);
        U[cb][m][1] = pk2bf(p[4 * m + 2], p[4 * m + 3]);
      }
    }

    // --- V B-frags; P A-frags via lane^32 exchange; PV ---
    short8 vb[2][4];
#pragma unroll
    for (int nb = 0; nb < 2; ++nb)
#pragma unroll
      for (int kc = 0; kc < 4; ++kc)
        vb[nb][kc] = *(const short8*)&Vt[nb * 32 + l31][(kc * 2 + h5) * 8];

#pragma unroll
    for (int kc = 0; kc < 4; ++kc) {
      const int cb = kc >> 1, k2 = (kc & 1) * 2;
      unsigned int su0 = h5 ? U[cb][k2 + 1][0] : U[cb][k2][0];
      unsigned int su1 = h5 ? U[cb][k2 + 1][1] : U[cb][k2][1];
      unsigned int st0 = h5 ? U[cb][k2][0] : U[cb][k2 + 1][0];
      unsigned int st1 = h5 ? U[cb][k2][1] : U[cb][k2 + 1][1];
      unsigned int x0 = (unsigned int)__shfl_xor((int)st0, 32);
      unsigned int x1 = (unsigned int)__shfl_xor((int)st1, 32);
      union { unsigned int u[4]; short8 v; } pa;
      pa.u[0] = h5 ? x0 : su0;
      pa.u[1] = h5 ? x1 : su1;
      pa.u[2] = h5 ? su0 : x0;
      pa.u[3] = h5 ? su1 : x1;
#pragma unroll
      for (int nb = 0; nb < 2; ++nb)
        o[nb] = MFMA32(pa.v, vb[nb][kc], o[nb]);
    }
  }

  // --- epilogue: denom = 1/(rowsum + 1), broadcast via LDS + barrier ---
  {
    float tot = ls + __shfl_xor(ls, 32);
    if (h5 == 0) dsh[w][l31] = 1.0f / (tot + 1.0f);
  }
  __syncthreads();
#pragma unroll
  for (int m = 0; m < 4; ++m) {
    f4 dn4 = *(const f4*)&dsh[w][m * 8 + h5 * 4];
#pragma unroll
    for (int rr = 0; rr < 4; ++rr) {
      int q = m * 8 + h5 * 4 + rr;
      size_t row = (size_t)(b * CN + q0 + q);
#pragma unroll
      for (int nb = 0; nb < 2; ++nb) {
        float val = o[nb][m * 4 + rr] * dn4[rr];
        xq[row * CE + h * CD + nb * 32 + l31] = f2bf(val);
      }
    }
  }
}

// ---------------------------------------------------------------------------
extern "C" void kernel_launch(void* const* d_in, const int* in_sizes, int n_in,
                              void* d_out, int out_size, void* d_ws, size_t ws_size,
                              hipStream_t stream) {
  const float* q    = (const float*)d_in[0];
  const float* kv   = (const float*)d_in[1];
  const int*   mask = (const int*)d_in[2];
  const float* Wq   = (const float*)d_in[3];
  const float* bq   = (const float*)d_in[4];
  const float* Wkv  = (const float*)d_in[5];
  const float* bkv  = (const float*)d_in[6];
  const float* Wo   = (const float*)d_in[7];
  const float* bo   = (const float*)d_in[8];
  (void)in_sizes; (void)n_in; (void)out_size; (void)ws_size;

  char* ws = (char*)d_ws;   // 48 MB + 16 KB (attn writes in-place into xq)
  unsigned short* WoT  = (unsigned short*)(ws);                        // 2 MB
  unsigned short* xq   = (unsigned short*)(ws + (2u  << 20));          // 8 MB
  unsigned short* xk   = (unsigned short*)(ws + (10u << 20));          // 8 MB (compact)
  unsigned short* xvT  = (unsigned short*)(ws + (18u << 20));          // 8 MB (compact)
  unsigned short* WqT  = (unsigned short*)(ws + (26u << 20));          // 2 MB
  unsigned short* WkvT = (unsigned short*)(ws + (28u << 20));          // 4 MB
  unsigned short* qbf  = (unsigned short*)(ws + (32u << 20));          // 8 MB
  unsigned short* kvbf = (unsigned short*)(ws + (40u << 20));          // 8 MB
  int*            cidx = (int*)(ws + (48u << 20));                     // 16 KB
  int*            cnt  = (int*)(ws + (48u << 20) + 16384);             // 8 B

  // transposes + mask compaction + q/kv f32->bf16 conversion
  prep<<<8194, 256, 0, stream>>>(Wq, Wkv, Wo, WqT, WkvT, WoT,
                                 q, kv, qbf, kvbf, mask, cidx, cnt);

  // fused: xq = (qbf @ Wq + bq) * SCALE_Q ; compacted xk/xvT from kvbf[kept]
  gemm_qkv<<<1536, 256, 0, stream>>>(qbf, WqT, bq, xq, kvbf, WkvT, bkv,
                                     xk, xvT, cidx, cnt);

  attn_fwd<<<CB * CH * 16, 256, 0, stream>>>(xq, xk, xvT, cnt);

  // out = attn @ Wo + bo  (f32 out; A = xq holds attn result in-place)
  gemm_o<<<512, 256, 0, stream>>>(xq, WoT, bo, (float*)d_out);
}